// Round 2
// baseline (2691.134 us; speedup 1.0000x reference)
//
#include <hip/hip_runtime.h>
#include <hip/hip_bf16.h>

// HMM backward recursion, B=32, T=256, H=1024, V=50257.
// y_s[b,i] = N_{s-1}[b] + log( sum_j expA[i,j] * Y_{s-1}[b,j] ) + e_t[b,i]
// with Y_s = exp(y_s - N_s), N_s = max_i y_{s-1}[b,i]

#define Hdim 1024
#define Bdim 32
#define Tdim 256
#define Vdim 50257
#define NWG  16
#define SLICE 64

typedef __attribute__((ext_vector_type(8))) __bf16 bf16x8;
typedef __attribute__((ext_vector_type(4))) float  f32x4;

// workspace layout (bytes)
#define OFF_ABF   0                          // exp(alpha) bf16: 2 MB
#define OFF_YBUF  2097152                    // 2 * 32*1024 bf16 = 131072
#define OFF_LBUF  (OFF_YBUF + 131072)        // 2 * 16*32 f32 = 4096
#define OFF_PSUM  (OFF_LBUF + 4096)          // 32 f32 (pad 128)
#define OFF_RBUF  (OFF_PSUM + 128)           // 32 f32 (pad 128)
#define OFF_FLG   (OFF_RBUF + 128)           // 2*16 flags, 64B apart = 2048
#define OFF_END0  (OFF_FLG + 2048)
#define OFF_E     (((OFF_END0) + 4095) & ~4095)
#define WS_E_NEED ((size_t)OFF_E + (size_t)Tdim * Bdim * Hdim * 4)

// LDS carve
#define SM_A       131072                    // 64 rows x 1024 bf16 (swizzled)
#define SM_GSH     (SM_A)                    // 32 f32
#define SM_LTILE   (SM_GSH + 128)            // 4*32 f32
#define SMEM_BYTES (SM_LTILE + 512)

__global__ void k_expA(const float* __restrict__ alpha, __bf16* __restrict__ Abf) {
    int idx = (blockIdx.x * 256 + threadIdx.x) * 4;
    float4 v = *(const float4*)(alpha + idx);
    union { __bf16 h[4]; uint2 u; } cv;
    cv.h[0] = (__bf16)__expf(v.x);
    cv.h[1] = (__bf16)__expf(v.y);
    cv.h[2] = (__bf16)__expf(v.z);
    cv.h[3] = (__bf16)__expf(v.w);
    *(uint2*)(Abf + idx) = cv.u;
}

// Full-device scatter-gather: E[t][b][i] = beta[i, x[b,t]]
__global__ void k_gather(const int* __restrict__ x, const float* __restrict__ beta,
                         float* __restrict__ E) {
    int tb = blockIdx.x;            // 0..8191 : t*32 + b
    int t  = tb >> 5, b = tb & 31;
    int xv = x[b * Tdim + t];
    int i  = threadIdx.x * 4;
    float4 v;
    v.x = beta[(size_t)(i + 0) * Vdim + xv];
    v.y = beta[(size_t)(i + 1) * Vdim + xv];
    v.z = beta[(size_t)(i + 2) * Vdim + xv];
    v.w = beta[(size_t)(i + 3) * Vdim + xv];
    *(float4*)(E + ((size_t)t * Bdim + b) * Hdim + i) = v;
}

__device__ __forceinline__ void wait_flags(unsigned* flg, int par, unsigned want) {
    if (threadIdx.x < 64) {
        unsigned* fp = flg + ((size_t)par * 16 + (threadIdx.x & 15)) * 16;
        while (!__all((int)(__hip_atomic_load(fp, __ATOMIC_RELAXED, __HIP_MEMORY_SCOPE_AGENT) >= want)))
            __builtin_amdgcn_s_sleep(1);
        __builtin_amdgcn_fence(__ATOMIC_ACQUIRE, "agent");
    }
    __syncthreads();
}

__device__ __forceinline__ void load_e(const float* __restrict__ E,
                                       const float* __restrict__ beta,
                                       const int* __restrict__ x,
                                       int t, int b0, int i0, int useE, float e[2][4]) {
    if (useE) {
        #pragma unroll
        for (int u = 0; u < 2; ++u)
            #pragma unroll
            for (int r = 0; r < 4; ++r)
                e[u][r] = E[((size_t)t * Bdim + (b0 + r)) * Hdim + i0 + u * 16];
    } else {
        int xv[4];
        #pragma unroll
        for (int r = 0; r < 4; ++r) xv[r] = x[(b0 + r) * Tdim + t];
        #pragma unroll
        for (int u = 0; u < 2; ++u)
            #pragma unroll
            for (int r = 0; r < 4; ++r)
                e[u][r] = beta[(size_t)(i0 + u * 16) * Vdim + xv[r]];
    }
}

// write Y = exp(y - Gc) slice, publish per-WG per-b max of y
__device__ __forceinline__ void store_phase(const float y[2][4], const float Gc[4],
                                            __bf16* Ybw, float* Lbw, float* Ltile,
                                            int w, int li, int b0, int i0, int p) {
    #pragma unroll
    for (int r = 0; r < 4; ++r) {
        #pragma unroll
        for (int u = 0; u < 2; ++u) {
            float Yn = __expf(y[u][r] - Gc[r]);
            Ybw[(b0 + r) * Hdim + i0 + u * 16] = (__bf16)Yn;
        }
        float m = fmaxf(y[0][r], y[1][r]);
        m = fmaxf(m, __shfl_xor(m, 1, 16));
        m = fmaxf(m, __shfl_xor(m, 2, 16));
        m = fmaxf(m, __shfl_xor(m, 4, 16));
        m = fmaxf(m, __shfl_xor(m, 8, 16));
        if (li == 0) Ltile[w * 32 + b0 + r] = m;
    }
    __syncthreads();
    if (threadIdx.x < 32) {
        int b = threadIdx.x;
        int mbb = b >> 4;
        float L = fmaxf(Ltile[mbb * 32 + b], Ltile[(mbb + 2) * 32 + b]);
        Lbw[p * 32 + b] = L;
    }
}

__launch_bounds__(256, 1)
__global__ void k_hmm(const int* __restrict__ x,
                      const float* __restrict__ beta,
                      const float* __restrict__ gamma,
                      const __bf16* __restrict__ Abf,
                      __bf16* __restrict__ Ybuf,    // [2][32][1024]
                      float* __restrict__ Lbuf,     // [2][16][32]
                      float* __restrict__ Psum,
                      float* __restrict__ Rbuf,
                      unsigned* flg,                // [2][16] seq flags, 64B stride
                      const float* __restrict__ Ebuf,
                      int useE)
{
    extern __shared__ char smem[];
    char*  Asl   = smem;
    float* Gsh   = (float*)(smem + SM_GSH);
    float* Ltile = (float*)(smem + SM_LTILE);

    const int p   = blockIdx.x;
    const int tid = threadIdx.x;
    const int w   = tid >> 6;
    const int l   = tid & 63;
    const int g   = l >> 4;
    const int li  = l & 15;
    const int mb  = w & 1;
    const int np  = w >> 1;
    const int b0  = mb * 16 + g * 4;
    const int i0  = p * SLICE + np * 32 + li;

    // ---- stage A slice into LDS, XOR-swizzled for b128 reads ----
    #pragma unroll
    for (int rep = 0; rep < 32; ++rep) {
        int flat = rep * 256 + tid;
        int row  = flat >> 7;
        int c16  = flat & 127;
        uint4 v = *(const uint4*)((const char*)Abf + (size_t)(p * 64 + row) * 2048 + c16 * 16);
        int off = (row * 2048 + c16 * 16) ^ ((row & 7) << 4);
        *(uint4*)(Asl + off) = v;
    }
    __syncthreads();

    // ---- init: y0 = e[:, T-1] ----
    {
        float y0[2][4];
        load_e(Ebuf, beta, x, Tdim - 1, b0, i0, useE, y0);
        float Gc0[4] = {0.f, 0.f, 0.f, 0.f};
        store_phase(y0, Gc0, Ybuf, Lbuf, Ltile, w, li, b0, i0, p);
        __syncthreads();
        if (tid == 0)
            __hip_atomic_store(flg + (size_t)p * 16, 1u, __ATOMIC_RELEASE, __HIP_MEMORY_SCOPE_AGENT);
    }

    float Nprev[4] = {0.f, 0.f, 0.f, 0.f};
    float ereg[2][4];
    load_e(Ebuf, beta, x, Tdim - 2, b0, i0, useE, ereg);   // for s=1

    for (int s = 1; s < Tdim; ++s) {
        const int t     = Tdim - 1 - s;
        const int par_r = (s - 1) & 1;
        const int par_w = s & 1;
        const __bf16* Ybr = Ybuf + par_r * (Bdim * Hdim);
        __bf16*       Ybw = Ybuf + par_w * (Bdim * Hdim);
        const float*  Lbr = Lbuf + par_r * (NWG * 32);
        float*        Lbw = Lbuf + par_w * (NWG * 32);

        // prefetch next step's e (independent of flags/Y; overlaps poll+compute)
        float eregN[2][4];
        if (s < Tdim - 1) load_e(Ebuf, beta, x, t - 1, b0, i0, useE, eregN);

        float gl[2] = {0.f, 0.f};
        if (s == Tdim - 1) { gl[0] = gamma[i0]; gl[1] = gamma[i0 + 16]; }

        // wait for all producers of step s-1
        wait_flags(flg, par_r, (unsigned)s);

        // Y fragment loads straight into registers
        uint4 yreg[32];
        {
            const char* yrow = (const char*)Ybr + (size_t)(mb * 16 + li) * 2048 + g * 16;
            #pragma unroll
            for (int kc = 0; kc < 32; ++kc)
                yreg[kc] = *(const uint4*)(yrow + kc * 64);
        }

        // global max per b from published per-WG maxes
        if (tid < 32) {
            float gm = Lbr[tid];
            #pragma unroll
            for (int q = 1; q < NWG; ++q) gm = fmaxf(gm, Lbr[q * 32 + tid]);
            Gsh[tid] = gm;
        }
        __syncthreads();

        float Gcur[4];
        #pragma unroll
        for (int r = 0; r < 4; ++r) Gcur[r] = Gsh[b0 + r];

        // ---- S[b, i-slice] = sum_j expA[i,j] * Y[b,j] ----
        f32x4 acc0 = {0.f, 0.f, 0.f, 0.f}, acc1 = {0.f, 0.f, 0.f, 0.f};
        {
            const int ia = np * 32 + li;
            const int ib = ia + 16;
            const int basea = ia * 2048 + g * 16, xa = (ia & 7) << 4;
            const int baseb = ib * 2048 + g * 16, xb = (ib & 7) << 4;
            #pragma unroll
            for (int kc = 0; kc < 32; ++kc) {
                bf16x8 af0 = *(const bf16x8*)(Asl + ((basea + kc * 64) ^ xa));
                bf16x8 af1 = *(const bf16x8*)(Asl + ((baseb + kc * 64) ^ xb));
                bf16x8 yf  = __builtin_bit_cast(bf16x8, yreg[kc]);
                acc0 = __builtin_amdgcn_mfma_f32_16x16x32_bf16(yf, af0, acc0, 0, 0, 0);
                acc1 = __builtin_amdgcn_mfma_f32_16x16x32_bf16(yf, af1, acc1, 0, 0, 0);
            }
        }

        // ---- epilogue: y_s = N_{s-1} + log S + e_t ----
        float yv[2][4];
        #pragma unroll
        for (int r = 0; r < 4; ++r) {
            yv[0][r] = Nprev[r] + __logf(acc0[r]) + ereg[0][r];
            yv[1][r] = Nprev[r] + __logf(acc1[r]) + ereg[1][r];
        }

        if (s < Tdim - 1) {
            store_phase(yv, Gcur, Ybw, Lbw, Ltile, w, li, b0, i0, p);
            __syncthreads();
            if (tid == 0)
                __hip_atomic_store(flg + ((size_t)par_w * 16 + p) * 16, (unsigned)(s + 1),
                                   __ATOMIC_RELEASE, __HIP_MEMORY_SCOPE_AGENT);
            #pragma unroll
            for (int r = 0; r < 4; ++r) Nprev[r] = Gcur[r];
            #pragma unroll
            for (int u = 0; u < 2; ++u)
                #pragma unroll
                for (int r = 0; r < 4; ++r) ereg[u][r] = eregN[u][r];
        } else {
            #pragma unroll
            for (int r = 0; r < 4; ++r) {
                float pa = __expf(gl[0] + yv[0][r] - Gcur[r])
                         + __expf(gl[1] + yv[1][r] - Gcur[r]);
                pa += __shfl_xor(pa, 1, 16);
                pa += __shfl_xor(pa, 2, 16);
                pa += __shfl_xor(pa, 4, 16);
                pa += __shfl_xor(pa, 8, 16);
                if (li == 0) {
                    atomicAdd(&Psum[b0 + r], pa);
                    if (p == 0) Rbuf[b0 + r] = Gcur[r];
                }
            }
        }
    }
}

__global__ void k_final(const float* __restrict__ Psum, const float* __restrict__ Rbuf,
                        float* __restrict__ out) {
    int b = threadIdx.x;
    if (b < 32) out[b] = Rbuf[b] + __logf(Psum[b]);
}

extern "C" void kernel_launch(void* const* d_in, const int* in_sizes, int n_in,
                              void* d_out, int out_size, void* d_ws, size_t ws_size,
                              hipStream_t stream) {
    const int*   x     = (const int*)d_in[0];
    const float* alpha = (const float*)d_in[1];
    const float* beta  = (const float*)d_in[2];
    const float* gamma = (const float*)d_in[3];

    char* ws = (char*)d_ws;
    __bf16*   Abf  = (__bf16*)(ws + OFF_ABF);
    __bf16*   Ybuf = (__bf16*)(ws + OFF_YBUF);
    float*    Lbuf = (float*)(ws + OFF_LBUF);
    float*    Psum = (float*)(ws + OFF_PSUM);
    float*    Rbuf = (float*)(ws + OFF_RBUF);
    unsigned* flg  = (unsigned*)(ws + OFF_FLG);
    float*    Ebuf = (float*)(ws + OFF_E);

    int useE = (ws_size >= WS_E_NEED) ? 1 : 0;

    // zero Psum/Rbuf/flags every launch (harness poisons ws once, never restores)
    hipMemsetAsync(ws + OFF_PSUM, 0, OFF_END0 - OFF_PSUM, stream);

    hipLaunchKernelGGL(k_expA, dim3((Hdim * Hdim) / (256 * 4)), dim3(256), 0, stream, alpha, Abf);

    if (useE)
        hipLaunchKernelGGL(k_gather, dim3(Tdim * Bdim), dim3(256), 0, stream, x, beta, Ebuf);

    hipFuncSetAttribute((const void*)k_hmm, hipFuncAttributeMaxDynamicSharedMemorySize, SMEM_BYTES);
    hipLaunchKernelGGL(k_hmm, dim3(NWG), dim3(256), SMEM_BYTES, stream,
                       x, beta, gamma, Abf, Ybuf, Lbuf, Psum, Rbuf, flg,
                       useE ? Ebuf : (const float*)nullptr, useE);

    hipLaunchKernelGGL(k_final, dim3(1), dim3(64), 0, stream, Psum, Rbuf, (float*)d_out);
}

// Round 4
// 2118.592 us; speedup vs baseline: 1.2702x; 1.2702x over previous
//
#include <hip/hip_runtime.h>
#include <hip/hip_bf16.h>

// HMM backward recursion, B=32, T=256, H=1024, V=50257.
// y_s[b,i] = N_{s-1}[b] + log( sum_j expA[i,j] * Y_{s-1}[b,j] ) + e_t[b,i]
// Y_s = exp(y_s - N_s), N_s = max_i y_{s-1}[b,i] (one-step-stale upper bound).
// Exchange between the 16 persistent WGs is done entirely with sc0/sc1
// cache-bypassing loads/stores through the memory-side L3 (no L2 fences).

#define Hdim 1024
#define Bdim 32
#define Tdim 256
#define Vdim 50257
#define NWG  16
#define SLICE 64

typedef __attribute__((ext_vector_type(8))) __bf16 bf16x8;
typedef __attribute__((ext_vector_type(4))) float  f32x4;
typedef __attribute__((ext_vector_type(4))) unsigned u32x4;   // native vec for asm "v"

// workspace layout (bytes)
#define OFF_ABF   0                          // exp(alpha) bf16: 2 MB
#define OFF_YBUF  2097152                    // [2][16][32][64] bf16 = 131072
#define OFF_PSUM  (OFF_YBUF + 131072)        // 32 f32 (pad 128)
#define OFF_RBUF  (OFF_PSUM + 128)           // 32 f32 (pad 128)
#define OFF_LREC  (OFF_RBUF + 128)           // [2][16] records x 256 B = 8192
#define OFF_END0  (OFF_LREC + 8192)
#define OFF_E     (((OFF_END0) + 4095) & ~4095)
#define WS_E_NEED ((size_t)OFF_E + (size_t)Tdim * Bdim * Hdim * 4)

// LDS carve
#define SM_A       131072                    // 64 rows x 1024 bf16 (swizzled)
#define SM_YSH     (SM_A)                    // 32 x 64 bf16 = 4096
#define SM_GSH     (SM_YSH + 4096)           // 32 f32
#define SM_LTILE   (SM_GSH + 128)            // 4*32 f32
#define SMEM_BYTES (SM_LTILE + 512)

// ---- sc0/sc1 (device-scope, L2-bypassing) direct-L3 access helpers ----
__device__ __forceinline__ void st_b128_sc(void* p, u32x4 v) {
    asm volatile("global_store_dwordx4 %0, %1, off sc0 sc1" :: "v"(p), "v"(v) : "memory");
}
__device__ __forceinline__ void st_b32_sc(void* p, unsigned v) {
    asm volatile("global_store_dword %0, %1, off sc0 sc1" :: "v"(p), "v"(v) : "memory");
}
__device__ __forceinline__ void st_f32_sc(void* p, float v) {
    asm volatile("global_store_dword %0, %1, off sc0 sc1" :: "v"(p), "v"(v) : "memory");
}
__device__ __forceinline__ u32x4 ld_b128_sc(const void* p) {
    u32x4 r;
    asm volatile("global_load_dwordx4 %0, %1, off sc0 sc1" : "=v"(r) : "v"(p) : "memory");
    return r;
}
__device__ __forceinline__ float ld_f32_sc(const void* p) {
    float r;
    asm volatile("global_load_dword %0, %1, off sc0 sc1" : "=v"(r) : "v"(p) : "memory");
    return r;
}
__device__ __forceinline__ void waitcnt_vm0() {
    asm volatile("s_waitcnt vmcnt(0)" ::: "memory");
    __builtin_amdgcn_sched_barrier(0);
}

__global__ void k_expA(const float* __restrict__ alpha, __bf16* __restrict__ Abf) {
    int idx = (blockIdx.x * 256 + threadIdx.x) * 4;
    float4 v = *(const float4*)(alpha + idx);
    union { __bf16 h[4]; uint2 u; } cv;
    cv.h[0] = (__bf16)__expf(v.x);
    cv.h[1] = (__bf16)__expf(v.y);
    cv.h[2] = (__bf16)__expf(v.z);
    cv.h[3] = (__bf16)__expf(v.w);
    *(uint2*)(Abf + idx) = cv.u;
}

// Full-device scatter-gather: E[t][b][i] = beta[i, x[b,t]]
__global__ void k_gather(const int* __restrict__ x, const float* __restrict__ beta,
                         float* __restrict__ E) {
    int tb = blockIdx.x;            // t*32 + b
    int t  = tb >> 5, b = tb & 31;
    int xv = x[b * Tdim + t];
    int i  = threadIdx.x * 4;
    float4 v;
    v.x = beta[(size_t)(i + 0) * Vdim + xv];
    v.y = beta[(size_t)(i + 1) * Vdim + xv];
    v.z = beta[(size_t)(i + 2) * Vdim + xv];
    v.w = beta[(size_t)(i + 3) * Vdim + xv];
    *(float4*)(E + ((size_t)t * Bdim + b) * Hdim + i) = v;
}

__device__ __forceinline__ void wait_flags(const char* lrec, int par, unsigned want) {
    if (threadIdx.x < 64) {
        const unsigned* fp =
            (const unsigned*)(lrec + ((size_t)par * NWG + (threadIdx.x & 15)) * 256 + 128);
        while (!__all((int)(__hip_atomic_load(fp, __ATOMIC_RELAXED, __HIP_MEMORY_SCOPE_AGENT) >= want)))
            __builtin_amdgcn_s_sleep(1);
    }
    __syncthreads();
}

__device__ __forceinline__ void load_e(const float* __restrict__ E,
                                       const float* __restrict__ beta,
                                       const int* __restrict__ x,
                                       int t, int b0, int i0, int useE, float e[2][4]) {
    if (useE) {
        #pragma unroll
        for (int u = 0; u < 2; ++u)
            #pragma unroll
            for (int r = 0; r < 4; ++r)
                e[u][r] = E[((size_t)t * Bdim + (b0 + r)) * Hdim + i0 + u * 16];
    } else {
        int xv[4];
        #pragma unroll
        for (int r = 0; r < 4; ++r) xv[r] = x[(b0 + r) * Tdim + t];
        #pragma unroll
        for (int u = 0; u < 2; ++u)
            #pragma unroll
            for (int r = 0; r < 4; ++r)
                e[u][r] = beta[(size_t)(i0 + u * 16) * Vdim + xv[r]];
    }
}

// Publish: Y-slice (LDS-staged, contiguous 4KB sc-store), per-WG per-b max, then flag.
__device__ __forceinline__ void store_phase(const float y[2][4], const float Gc[4],
                                            char* Yblk,   // Ybuf[par] + p*4096
                                            char* Lrec_p, // record (par,p)
                                            __bf16* Ysh, float* Ltile,
                                            int w, int li, int g, int np, int b0,
                                            unsigned seq) {
    #pragma unroll
    for (int r = 0; r < 4; ++r) {
        #pragma unroll
        for (int u = 0; u < 2; ++u) {
            float Yn = __expf(y[u][r] - Gc[r]);
            Ysh[(b0 + r) * 64 + np * 32 + u * 16 + li] = (__bf16)Yn;
        }
        float m = fmaxf(y[0][r], y[1][r]);
        m = fmaxf(m, __shfl_xor(m, 1, 16));
        m = fmaxf(m, __shfl_xor(m, 2, 16));
        m = fmaxf(m, __shfl_xor(m, 4, 16));
        m = fmaxf(m, __shfl_xor(m, 8, 16));
        if (li == 0) Ltile[w * 32 + b0 + r] = m;
    }
    __syncthreads();
    const int tid = threadIdx.x;
    st_b128_sc(Yblk + tid * 16, ((const u32x4*)Ysh)[tid]);
    if (tid < 32) {
        int mbb = tid >> 4;
        float L = fmaxf(Ltile[mbb * 32 + tid], Ltile[(mbb + 2) * 32 + tid]);
        st_f32_sc(Lrec_p + tid * 4, L);
    }
    asm volatile("s_waitcnt vmcnt(0)" ::: "memory");
    __syncthreads();
    if (tid == 0) st_b32_sc(Lrec_p + 128, seq);
}

__launch_bounds__(256, 1)
__global__ void k_hmm(const int* __restrict__ x,
                      const float* __restrict__ beta,
                      const float* __restrict__ gamma,
                      const __bf16* __restrict__ Abf,
                      char* __restrict__ Yb,        // OFF_YBUF: [2][16][4096B]
                      char* __restrict__ lrec,      // OFF_LREC
                      float* __restrict__ Psum,
                      float* __restrict__ Rbuf,
                      const float* __restrict__ Ebuf,
                      int useE)
{
    extern __shared__ char smem[];
    char*   Asl   = smem;
    __bf16* Ysh   = (__bf16*)(smem + SM_YSH);
    float*  Gsh   = (float*)(smem + SM_GSH);
    float*  Ltile = (float*)(smem + SM_LTILE);

    const int p   = blockIdx.x;
    const int tid = threadIdx.x;
    const int w   = tid >> 6;
    const int l   = tid & 63;
    const int g   = l >> 4;
    const int li  = l & 15;
    const int mb  = w & 1;
    const int np  = w >> 1;
    const int b0  = mb * 16 + g * 4;
    const int i0  = p * SLICE + np * 32 + li;

    // ---- stage A slice into LDS, XOR-swizzled for b128 reads ----
    #pragma unroll
    for (int rep = 0; rep < 32; ++rep) {
        int flat = rep * 256 + tid;
        int row  = flat >> 7;
        int c16  = flat & 127;
        uint4 v = *(const uint4*)((const char*)Abf + (size_t)(p * 64 + row) * 2048 + c16 * 16);
        int off = (row * 2048 + c16 * 16) ^ ((row & 7) << 4);
        *(uint4*)(Asl + off) = v;
    }
    __syncthreads();

    // ---- init: y0 = e[:, T-1] ----
    {
        float y0[2][4];
        load_e(Ebuf, beta, x, Tdim - 1, b0, i0, useE, y0);
        float Gc0[4] = {0.f, 0.f, 0.f, 0.f};
        store_phase(y0, Gc0, Yb + p * 4096, lrec + (size_t)p * 256,
                    Ysh, Ltile, w, li, g, np, b0, 1u);
    }

    float Nprev[4] = {0.f, 0.f, 0.f, 0.f};
    float ereg[2][4];
    load_e(Ebuf, beta, x, Tdim - 2, b0, i0, useE, ereg);

    for (int s = 1; s < Tdim; ++s) {
        const int t     = Tdim - 1 - s;
        const int par_r = (s - 1) & 1;
        const int par_w = s & 1;

        // prefetch next step's e (overlaps flag poll)
        float eregN[2][4];
        if (s < Tdim - 1) load_e(Ebuf, beta, x, t - 1, b0, i0, useE, eregN);

        float gl[2] = {0.f, 0.f};
        if (s == Tdim - 1) { gl[0] = gamma[i0]; gl[1] = gamma[i0 + 16]; }

        wait_flags(lrec, par_r, (unsigned)s);

        // Y fragment loads (sc-bypass, direct L3): layout [blk=j>>6][b][j&63]
        const char* Ybase = Yb + (size_t)par_r * (NWG * 4096);
        const char* yrow  = Ybase + (mb * 16 + li) * 128 + g * 16;
        u32x4 yreg[32];
        #pragma unroll
        for (int kc = 0; kc < 32; ++kc)
            yreg[kc] = ld_b128_sc(yrow + (kc >> 1) * 4096 + (kc & 1) * 64);

        // per-WG maxes (sc-bypass); reduce after the single vmcnt drain
        float gmv[16];
        const char* lbase = lrec + (size_t)par_r * NWG * 256;
        if (tid < 32) {
            #pragma unroll
            for (int q = 0; q < 16; ++q)
                gmv[q] = ld_f32_sc(lbase + q * 256 + tid * 4);
        }

        waitcnt_vm0();

        if (tid < 32) {
            float gm = gmv[0];
            #pragma unroll
            for (int q = 1; q < 16; ++q) gm = fmaxf(gm, gmv[q]);
            Gsh[tid] = gm;
        }
        __syncthreads();

        // ---- S[b, i-slice] = sum_j expA[i,j] * Y[b,j] ----
        f32x4 acc0 = {0.f, 0.f, 0.f, 0.f}, acc1 = {0.f, 0.f, 0.f, 0.f};
        {
            const int ia = np * 32 + li;
            const int ib = ia + 16;
            const int basea = ia * 2048 + g * 16, xa = (ia & 7) << 4;
            const int baseb = ib * 2048 + g * 16, xb = (ib & 7) << 4;
            #pragma unroll
            for (int kc = 0; kc < 32; ++kc) {
                bf16x8 af0 = *(const bf16x8*)(Asl + ((basea + kc * 64) ^ xa));
                bf16x8 af1 = *(const bf16x8*)(Asl + ((baseb + kc * 64) ^ xb));
                bf16x8 yf  = __builtin_bit_cast(bf16x8, yreg[kc]);
                acc0 = __builtin_amdgcn_mfma_f32_16x16x32_bf16(yf, af0, acc0, 0, 0, 0);
                acc1 = __builtin_amdgcn_mfma_f32_16x16x32_bf16(yf, af1, acc1, 0, 0, 0);
            }
        }

        float Gcur[4];
        #pragma unroll
        for (int r = 0; r < 4; ++r) Gcur[r] = Gsh[b0 + r];

        float yv[2][4];
        #pragma unroll
        for (int r = 0; r < 4; ++r) {
            yv[0][r] = Nprev[r] + __logf(acc0[r]) + ereg[0][r];
            yv[1][r] = Nprev[r] + __logf(acc1[r]) + ereg[1][r];
        }

        if (s < Tdim - 1) {
            store_phase(yv, Gcur, Yb + (size_t)par_w * (NWG * 4096) + p * 4096,
                        lrec + ((size_t)par_w * NWG + p) * 256,
                        Ysh, Ltile, w, li, g, np, b0, (unsigned)(s + 1));
            #pragma unroll
            for (int r = 0; r < 4; ++r) Nprev[r] = Gcur[r];
            #pragma unroll
            for (int u = 0; u < 2; ++u)
                #pragma unroll
                for (int r = 0; r < 4; ++r) ereg[u][r] = eregN[u][r];
        } else {
            #pragma unroll
            for (int r = 0; r < 4; ++r) {
                float pa = __expf(gl[0] + yv[0][r] - Gcur[r])
                         + __expf(gl[1] + yv[1][r] - Gcur[r]);
                pa += __shfl_xor(pa, 1, 16);
                pa += __shfl_xor(pa, 2, 16);
                pa += __shfl_xor(pa, 4, 16);
                pa += __shfl_xor(pa, 8, 16);
                if (li == 0) {
                    atomicAdd(&Psum[b0 + r], pa);
                    if (p == 0) Rbuf[b0 + r] = Gcur[r];
                }
            }
        }
    }
}

__global__ void k_final(const float* __restrict__ Psum, const float* __restrict__ Rbuf,
                        float* __restrict__ out) {
    int b = threadIdx.x;
    if (b < 32) out[b] = Rbuf[b] + __logf(Psum[b]);
}

extern "C" void kernel_launch(void* const* d_in, const int* in_sizes, int n_in,
                              void* d_out, int out_size, void* d_ws, size_t ws_size,
                              hipStream_t stream) {
    const int*   x     = (const int*)d_in[0];
    const float* alpha = (const float*)d_in[1];
    const float* beta  = (const float*)d_in[2];
    const float* gamma = (const float*)d_in[3];

    char* ws = (char*)d_ws;
    __bf16* Abf  = (__bf16*)(ws + OFF_ABF);
    char*   Yb   = ws + OFF_YBUF;
    float*  Psum = (float*)(ws + OFF_PSUM);
    float*  Rbuf = (float*)(ws + OFF_RBUF);
    char*   lrec = ws + OFF_LREC;
    float*  Ebuf = (float*)(ws + OFF_E);

    int useE = (ws_size >= WS_E_NEED) ? 1 : 0;

    // zero Psum/Rbuf/records every launch
    (void)hipMemsetAsync(ws + OFF_PSUM, 0, OFF_END0 - OFF_PSUM, stream);

    hipLaunchKernelGGL(k_expA, dim3((Hdim * Hdim) / (256 * 4)), dim3(256), 0, stream, alpha, Abf);

    if (useE)
        hipLaunchKernelGGL(k_gather, dim3(Tdim * Bdim), dim3(256), 0, stream, x, beta, Ebuf);

    (void)hipFuncSetAttribute((const void*)k_hmm, hipFuncAttributeMaxDynamicSharedMemorySize, SMEM_BYTES);
    hipLaunchKernelGGL(k_hmm, dim3(NWG), dim3(256), SMEM_BYTES, stream,
                       x, beta, gamma, Abf, Yb, lrec, Psum, Rbuf,
                       useE ? Ebuf : (const float*)nullptr, useE);

    hipLaunchKernelGGL(k_final, dim3(1), dim3(64), 0, stream, Psum, Rbuf, (float*)d_out);
}